// Round 6
// baseline (284.032 us; speedup 1.0000x reference)
//
#include <hip/hip_runtime.h>

typedef unsigned short u16;
typedef unsigned int u32;
typedef u16 u16x4 __attribute__((ext_vector_type(4)));
typedef u16 u16x8 __attribute__((ext_vector_type(8)));
typedef u32 u32x4 __attribute__((ext_vector_type(4)));
typedef __bf16 bf16x8 __attribute__((ext_vector_type(8)));
typedef float f32x16 __attribute__((ext_vector_type(16)));

#define NB   2
#define NQH  32
#define NKH  8
#define SEQ  2048
#define DIM  128
#define BKV  64
#define QT   128                      // q rows per block (32 per wave, 32x32 MFMA)
#define NTILE   (SEQ / BKV)           // 32
#define TILEU16 (BKV * DIM)           // 8192 u16 = 16KB per image tile
#define VOFFU16 (16 * NTILE * TILEU16)

__device__ __forceinline__ u16 f2bf(float f) {
  u32 u = __builtin_bit_cast(u32, f);
  u += 0x7FFFu + ((u >> 16) & 1u);
  return (u16)(u >> 16);
}
__device__ __forceinline__ u32 cvtpk(float lo, float hi) {
  u32 r;
  asm("v_cvt_pk_bf16_f32 %0, %1, %2" : "=v"(r) : "v"(lo), "v"(hi));
  return r;
}
__device__ __forceinline__ f32x16 mfma32(u16x8 a, u16x8 b, f32x16 c) {
  return __builtin_amdgcn_mfma_f32_32x32x16_bf16(
      __builtin_bit_cast(bf16x8, a), __builtin_bit_cast(bf16x8, b), c, 0, 0, 0);
}
__device__ __forceinline__ void gl_lds16(const u16* g, u16* l) {
  __builtin_amdgcn_global_load_lds(
      (const __attribute__((address_space(1))) u32*)(const void*)g,
      (__attribute__((address_space(3))) u32*)(void*)l, 16, 0, 0);
}

// ---- pre-pass: swizzled bf16 images ----
// K image tile t: u16 idx j*128 + (dm ^ ((j&7)<<3)) = bf16 K[j][dm]   (j=key,dm=d)
// V image tile t: u16 idx d*64 + ((p&~7) ^ ((d&7)<<3)) + (p&7) = bf16 V[key(p)][d]
//   key(p) = swap bits 2<->3 of p   (sigma' matching the PV A-frag bitcast)
__global__ __launch_bounds__(256) void prep(const float* __restrict__ Kg,
                                            const float* __restrict__ Vg,
                                            u16* __restrict__ ws) {
  const int bid = blockIdx.x;          // 0..1023 : first 512 K, next 512 V
  const int tid = threadIdx.x;
  const int tile = bid & 511;          // bkh*32 + kt
  const size_t sbase = (size_t)(tile >> 5) * SEQ * DIM + (size_t)(tile & 31) * BKV * DIM;
  if (bid < 512) {
    const float* src = Kg + sbase;
    u16* img = ws + (size_t)tile * TILEU16;
    #pragma unroll
    for (int u = 0; u < 8; ++u) {
      int c = tid + 256 * u;           // float4 chunk 0..2047
      int j = c >> 5;
      int dm = (c & 31) * 4;
      float4 v = *(const float4*)(src + j * DIM + dm);
      u16x4 w = { f2bf(v.x), f2bf(v.y), f2bf(v.z), f2bf(v.w) };
      *(u16x4*)(img + j * 128 + (dm ^ ((j & 7) << 3))) = w;
    }
  } else {
    const float* src = Vg + sbase;
    u16* img = ws + VOFFU16 + (size_t)tile * TILEU16;
    #pragma unroll
    for (int u = 0; u < 4; ++u) {
      int c = tid + 256 * u;           // u16x8 granule 0..1023
      int d = c >> 3;
      int pg = c & 7;                  // granule of 8 slots
      u16x8 w;
      #pragma unroll
      for (int i = 0; i < 8; ++i) {
        int p = 8 * pg + i;
        int key = (p & ~12) | ((p & 8) >> 1) | ((p & 4) << 1);  // swap bits 2,3
        w[i] = f2bf(src[key * DIM + d]);
      }
      *(u16x8*)(img + d * 64 + ((8 * pg) ^ ((d & 7) << 3))) = w;
    }
  }
}

__global__ __launch_bounds__(256) void gqa_fwd(const float* __restrict__ Qg,
                                               const u16* __restrict__ ws,
                                               float* __restrict__ Og) {
  __shared__ __align__(16) u16 sK[2][TILEU16];
  __shared__ __align__(16) u16 sV[2][TILEU16];

  const int tid  = threadIdx.x;
  const int lane = tid & 63;
  const int wave = tid >> 6;
  const int l31  = lane & 31;
  const int h    = lane >> 5;

  // XCD-aware swizzle: grid = 1024 blocks, 8 XCDs -> each XCD a contiguous
  // run of 128 logical ids (8 bqh groups x 16 qtiles; KV images L2-resident).
  const int id = blockIdx.x;           // 0..1023
  const int wg = (id & 7) * 128 + (id >> 3);
  const int qtile = wg & 15;           // 0..15
  const int bqh   = wg >> 4;           // 0..63
  const int b     = bqh >> 5;
  const int qh    = bqh & 31;
  const int kh    = qh >> 2;           // G = 4

  const size_t qbase = (size_t)bqh * SEQ * DIM;
  const u16* imgK = ws + (size_t)((b * NKH + kh) * NTILE) * TILEU16;
  const u16* imgV = imgK + VOFFU16;
  const int qrow_w = qtile * QT + wave * 32;

  // log2-domain scale: 1/sqrt(128) * log2(e)
  const float s2 = 0.08838834764831845f * 1.4426950408889634f;

  // Q frags (B-operand 32x32x16): qf[s8][e] = Q[q=l31][d=16*s8+8*h+e] * s2
  u16x8 qf[8];
  #pragma unroll
  for (int s8 = 0; s8 < 8; ++s8) {
    const float* qp = Qg + qbase + (size_t)(qrow_w + l31) * DIM + 16 * s8 + 8 * h;
    float4 a = *(const float4*)qp;
    float4 c = *(const float4*)(qp + 4);
    qf[s8] = __builtin_bit_cast(u16x8, u32x4{
        cvtpk(a.x * s2, a.y * s2), cvtpk(a.z * s2, a.w * s2),
        cvtpk(c.x * s2, c.y * s2), cvtpk(c.z * s2, c.w * s2) });
  }

  f32x16 oacc[4];
  #pragma unroll
  for (int dt = 0; dt < 4; ++dt)
    #pragma unroll
    for (int r = 0; r < 16; ++r) oacc[dt][r] = 0.f;
  float mrow = -3.0e38f, lrow = 0.f;

  auto issue = [&](int nk, int pb) {
    const u16* gK = imgK + (size_t)nk * TILEU16;
    const u16* gV = imgV + (size_t)nk * TILEU16;
    #pragma unroll
    for (int u = 0; u < 4; ++u) {
      const int q = u * 4 + wave;      // 1KB chunk 0..15
      gl_lds16(gK + q * 512 + lane * 8, &sK[pb][q * 512]);
      gl_lds16(gV + q * 512 + lane * 8, &sV[pb][q * 512]);
    }
  };

  auto tile_body = [&](int KT, int PB) {
    issue((KT + 1) & 31, PB ^ 1);      // prefetch next tile into other buffer
    asm volatile("s_waitcnt vmcnt(8)" ::: "memory");  // this tile's 8 loads done
    __builtin_amdgcn_s_barrier();      // raw barrier: keep prefetch in flight

    // ---- S^T = K Q^T : sac{0,1}[r] = S[key=32*b32+(r&3)+8*(r>>2)+4*h][q=l31]
    f32x16 sac0, sac1;
    #pragma unroll
    for (int r = 0; r < 16; ++r) { sac0[r] = 0.f; sac1[r] = 0.f; }
    const int swz = (l31 & 7) << 3;
    __builtin_amdgcn_s_setprio(1);
    #pragma unroll
    for (int s8 = 0; s8 < 8; ++s8) {
      u16x8 kf0 = *(const u16x8*)&sK[PB][l31 * 128 + ((16 * s8 + 8 * h) ^ swz)];
      u16x8 kf1 = *(const u16x8*)&sK[PB][(32 + l31) * 128 + ((16 * s8 + 8 * h) ^ swz)];
      sac0 = mfma32(kf0, qf[s8], sac0);
      sac1 = mfma32(kf1, qf[s8], sac1);
    }
    __builtin_amdgcn_s_setprio(0);

    // ---- online softmax (log2 domain), q-row = l31; partner lane = xor 32
    float tmax = -3.0e38f;
    #pragma unroll
    for (int r = 0; r < 16; ++r) tmax = fmaxf(tmax, fmaxf(sac0[r], sac1[r]));
    tmax = fmaxf(tmax, __shfl_xor(tmax, 32, 64));

    if (!__all(tmax - mrow <= 11.0f)) {   // defer-max (P bounded by 2^11)
      float mn = fmaxf(mrow, tmax);
      float corr = exp2f(mrow - mn);
      mrow = mn;
      lrow *= corr;
      #pragma unroll
      for (int r = 0; r < 16; ++r) {
        float co = __shfl(corr, (r & 3) + 8 * (r >> 2) + 4 * h, 64);
        oacc[0][r] *= co; oacc[1][r] *= co; oacc[2][r] *= co; oacc[3][r] *= co;
      }
    }

    float rsum = 0.f;
    #pragma unroll
    for (int r = 0; r < 16; ++r) {
      sac0[r] = exp2f(sac0[r] - mrow);
      sac1[r] = exp2f(sac1[r] - mrow);
      rsum += sac0[r] + sac1[r];
    }
    rsum += __shfl_xor(rsum, 32, 64);
    lrow += rsum;

    // ---- A-frags for PV: pure bitcast (sigma' folded into V image)
    u16x8 af[4];
    af[0] = __builtin_bit_cast(u16x8, u32x4{cvtpk(sac0[0], sac0[1]),  cvtpk(sac0[2], sac0[3]),
                                            cvtpk(sac0[4], sac0[5]),  cvtpk(sac0[6], sac0[7])});
    af[1] = __builtin_bit_cast(u16x8, u32x4{cvtpk(sac0[8], sac0[9]),  cvtpk(sac0[10], sac0[11]),
                                            cvtpk(sac0[12], sac0[13]), cvtpk(sac0[14], sac0[15])});
    af[2] = __builtin_bit_cast(u16x8, u32x4{cvtpk(sac1[0], sac1[1]),  cvtpk(sac1[2], sac1[3]),
                                            cvtpk(sac1[4], sac1[5]),  cvtpk(sac1[6], sac1[7])});
    af[3] = __builtin_bit_cast(u16x8, u32x4{cvtpk(sac1[8], sac1[9]),  cvtpk(sac1[10], sac1[11]),
                                            cvtpk(sac1[12], sac1[13]), cvtpk(sac1[14], sac1[15])});

    // ---- O += P V : vf = V^T image row d=32*dt+l31, slot chunk 16*c+8*h
    __builtin_amdgcn_s_setprio(1);
    #pragma unroll
    for (int dt = 0; dt < 4; ++dt) {
      #pragma unroll
      for (int c = 0; c < 4; ++c) {
        u16x8 vf = *(const u16x8*)&sV[PB][(32 * dt + l31) * 64 + ((16 * c + 8 * h) ^ swz)];
        oacc[dt] = mfma32(af[c], vf, oacc[dt]);
      }
    }
    __builtin_amdgcn_s_setprio(0);
    __builtin_amdgcn_s_barrier();      // all waves done reading buf[PB]
  };

  issue(0, 0);
  for (int kt2 = 0; kt2 < 16; ++kt2) {
    tile_body(2 * kt2, 0);
    tile_body(2 * kt2 + 1, 1);
  }
  asm volatile("s_waitcnt vmcnt(0)" ::: "memory");  // drain wrap-around prefetch

  // ---- epilogue: O[q = qrow_w+(r&3)+8*(r>>2)+4h][d = 32*dt + l31] / lrow
  float linv = 1.0f / lrow;
  #pragma unroll
  for (int r = 0; r < 16; ++r) {
    const int ql = (r & 3) + 8 * (r >> 2) + 4 * h;
    float li = __shfl(linv, ql, 64);
    float* op = Og + qbase + (size_t)(qrow_w + ql) * DIM + l31;
    op[0]  = oacc[0][r] * li;
    op[32] = oacc[1][r] * li;
    op[64] = oacc[2][r] * li;
    op[96] = oacc[3][r] * li;
  }
}

extern "C" void kernel_launch(void* const* d_in, const int* in_sizes, int n_in,
                              void* d_out, int out_size, void* d_ws, size_t ws_size,
                              hipStream_t stream) {
  const float* Q = (const float*)d_in[0];
  const float* K = (const float*)d_in[1];
  const float* V = (const float*)d_in[2];
  float* O = (float*)d_out;
  u16* ws = (u16*)d_ws;
  prep<<<dim3(1024), 256, 0, stream>>>(K, V, ws);
  gqa_fwd<<<dim3((SEQ / QT) * NB * NQH), 256, 0, stream>>>(Q, ws, O);
}